// Round 9
// baseline (294.795 us; speedup 1.0000x reference)
//
#include <hip/hip_runtime.h>

#define NGROUPS 256
#define NSHARD  8

typedef unsigned long long u64;

// ---- DPP 32-lane sum (pure VALU, no LDS pipe) ----
// row_shr:1/2/4/8 then row_bcast:15. Afterwards lane31 = sum(lanes 0..31),
// lane63 = sum(lanes 32..63). bound_ctrl=1 -> OOB source lanes contribute 0.
template<int CTRL>
__device__ __forceinline__ float dpp_add_f(float x) {
    int s = __builtin_amdgcn_update_dpp(0, __float_as_int(x), CTRL, 0xF, 0xF, true);
    return x + __int_as_float(s);
}
template<int CTRL>
__device__ __forceinline__ int dpp_add_i(int x) {
    return x + __builtin_amdgcn_update_dpp(0, x, CTRL, 0xF, 0xF, true);
}
__device__ __forceinline__ float half_sum_f(float x) {
    x = dpp_add_f<0x111>(x);
    x = dpp_add_f<0x112>(x);
    x = dpp_add_f<0x114>(x);
    x = dpp_add_f<0x118>(x);
    x = dpp_add_f<0x142>(x);
    return x;
}
__device__ __forceinline__ int half_sum_i(int x) {
    x = dpp_add_i<0x111>(x);
    x = dpp_add_i<0x112>(x);
    x = dpp_add_i<0x114>(x);
    x = dpp_add_i<0x118>(x);
    x = dpp_add_i<0x142>(x);
    return x;
}

// Zero the sharded global accumulators.
__global__ __launch_bounds__(256) void rrl_init(
    float* __restrict__ g_pos, float* __restrict__ g_neg, u64* __restrict__ g_cnt)
{
    for (int i = threadIdx.x; i < NSHARD * NGROUPS; i += 256) {
        g_pos[i] = 0.f; g_neg[i] = 0.f; g_cnt[i] = 0ULL;
    }
}

// Pass 1: pure streaming. Each 32-lane half-wave owns one row per slot
// (C=128 floats = 32 float4). Depth-4 unroll with independent registers:
// 8 global loads issued back-to-back, then 4 independent compute+DPP chains,
// then 2-lane plain stores of per-row {p, q, cnt}. No atomics, no LDS.
__device__ __forceinline__ void rrl_proc(
    float4 v, int4 t, int i, int lane31,
    float2* __restrict__ row_pq, unsigned* __restrict__ row_cnt)
{
    float e0 = __expf(v.x);
    float e1 = __expf(v.y);
    float e2 = __expf(v.z);
    float e3 = __expf(v.w);
    float p = 0.f, q = 0.f;
    int pc = 0, qc = 0;
    if (t.x != 0) { p += e0; ++pc; } else { q += e0; ++qc; }
    if (t.y != 0) { p += e1; ++pc; } else { q += e1; ++qc; }
    if (t.z != 0) { p += e2; ++pc; } else { q += e2; ++qc; }
    if (t.w != 0) { p += e3; ++pc; } else { q += e3; ++qc; }
    int cnt = pc | (qc << 16);          // per-row pc,qc <= 128 < 2^16
    p   = half_sum_f(p);
    q   = half_sum_f(q);
    cnt = half_sum_i(cnt);
    if (lane31 == 31) {                  // lanes 31 and 63 hold the half sums
        int r = i >> 5;                  // this lane's own row
        row_pq[r]  = make_float2(p, q);
        row_cnt[r] = (unsigned)cnt;
    }
}

__global__ __launch_bounds__(256, 8) void rrl_rows(
    const float4* __restrict__ x4,
    const int4*   __restrict__ t4,
    float2*   __restrict__ row_pq,
    unsigned* __restrict__ row_cnt,
    int n4)
{
    const int lane31 = threadIdx.x & 31;
    const int stride = gridDim.x * 256;
    int i = blockIdx.x * 256 + threadIdx.x;

    for (; i + 3 * stride < n4; i += 4 * stride) {
        int i1 = i + stride, i2 = i + 2 * stride, i3 = i + 3 * stride;
        float4 v0 = x4[i];  float4 v1 = x4[i1];
        float4 v2 = x4[i2]; float4 v3 = x4[i3];
        int4   t0 = t4[i];  int4   t1 = t4[i1];
        int4   t2 = t4[i2]; int4   t3 = t4[i3];
        rrl_proc(v0, t0, i,  lane31, row_pq, row_cnt);
        rrl_proc(v1, t1, i1, lane31, row_pq, row_cnt);
        rrl_proc(v2, t2, i2, lane31, row_pq, row_cnt);
        rrl_proc(v3, t3, i3, lane31, row_pq, row_cnt);
    }
    for (; i < n4; i += stride) {
        rrl_proc(x4[i], t4[i], i, lane31, row_pq, row_cnt);
    }
}

// Pass 2: bin 262144 per-row results into 256 groups. Lanes carry different
// rows -> random groups -> LDS atomic same-address collisions are rare.
__global__ __launch_bounds__(256) void rrl_bin(
    const float2*   __restrict__ row_pq,
    const unsigned* __restrict__ row_cnt,
    const int*      __restrict__ img_id,
    float* __restrict__ g_pos,      // [NSHARD][NGROUPS]
    float* __restrict__ g_neg,
    u64*   __restrict__ g_cnt,      // hi32 = neg count, lo32 = pos count
    int nrows)
{
    __shared__ float s_pos[NGROUPS];
    __shared__ float s_neg[NGROUPS];
    __shared__ u64   s_cnt[NGROUPS];
    for (int i = threadIdx.x; i < NGROUPS; i += 256) {
        s_pos[i] = 0.f; s_neg[i] = 0.f; s_cnt[i] = 0ULL;
    }
    __syncthreads();

    const int stride = gridDim.x * 256;
    for (int r = blockIdx.x * 256 + threadIdx.x; r < nrows; r += stride) {
        float2 pq = row_pq[r];
        unsigned c = row_cnt[r];
        int g = img_id[r];
        atomicAdd(&s_pos[g], pq.x);
        atomicAdd(&s_neg[g], pq.y);
        atomicAdd(&s_cnt[g], ((u64)(c >> 16) << 32) | (u64)(c & 0xffffu));
    }
    __syncthreads();

    const int shard = (blockIdx.x & (NSHARD - 1)) * NGROUPS;
    for (int g = threadIdx.x; g < NGROUPS; g += 256) {
        atomicAdd(&g_pos[shard + g], s_pos[g]);
        atomicAdd(&g_neg[shard + g], s_neg[g]);
        atomicAdd(&g_cnt[shard + g], s_cnt[g]);
    }
}

// Final: one block; thread g merges 8 shards, computes loss_g, reduces.
__global__ __launch_bounds__(256) void rrl_final(
    const float* __restrict__ g_pos,
    const float* __restrict__ g_neg,
    const u64*   __restrict__ g_cnt,
    float* __restrict__ out)
{
    const int g = threadIdx.x;
    double pos_sum = 0.0, neg_sum = 0.0;
    u64 cc = 0ULL;
    #pragma unroll
    for (int s = 0; s < NSHARD; ++s) {
        pos_sum += (double)g_pos[s * NGROUPS + g];
        neg_sum += (double)g_neg[s * NGROUPS + g];
        cc      += g_cnt[s * NGROUPS + g];
    }
    long long pc = (long long)(cc & 0xffffffffULL);
    long long nc = (long long)(cc >> 32);
    long long count = pc + nc;

    // Expected sum of the k = min(pc, nc) randomly-sampled negatives:
    // neg_sum * k / nc (exact when pc >= nc: all negatives selected).
    double sel = 0.0;
    if (nc > 0) {
        long long k = (pc < nc) ? pc : nc;
        sel = neg_sum * ((double)k / (double)nc);
    }
    double loss = 0.0;
    if (pc > 0) loss = -log(pos_sum / (pos_sum + sel));
    int present = (count > 0) ? 1 : 0;

    __shared__ double sl[256];
    __shared__ int    sp[256];
    sl[g] = loss; sp[g] = present;
    __syncthreads();
    for (int off = 128; off > 0; off >>= 1) {
        if (g < off) { sl[g] += sl[g + off]; sp[g] += sp[g + off]; }
        __syncthreads();
    }
    if (g == 0) {
        double npres = (sp[0] > 0) ? (double)sp[0] : 1.0;
        out[0] = (float)(sl[0] / npres);
    }
}

extern "C" void kernel_launch(void* const* d_in, const int* in_sizes, int n_in,
                              void* d_out, int out_size, void* d_ws, size_t ws_size,
                              hipStream_t stream) {
    const float4* x4  = (const float4*)d_in[0];
    const int4*   t4  = (const int4*)d_in[1];
    const int*    img = (const int*)d_in[2];
    float* out = (float*)d_out;

    const int NC    = in_sizes[0];    // N * C
    const int n4    = NC / 4;         // float4 count
    const int nrows = in_sizes[2];    // N (img_id length)

    // ws: row_pq [N] float2 (2MB), row_cnt [N] u32 (1MB), then sharded accums.
    char* w = (char*)d_ws;
    float2*   row_pq  = (float2*)w;   w += (size_t)nrows * 8;
    unsigned* row_cnt = (unsigned*)w; w += (size_t)nrows * 4;
    float* g_pos = (float*)w;         w += (size_t)NSHARD * NGROUPS * 4;
    float* g_neg = (float*)w;         w += (size_t)NSHARD * NGROUPS * 4;
    u64*   g_cnt = (u64*)w;

    const int NB = 2048;              // 8 blocks/CU on 256 CUs

    rrl_init <<<1, 256, 0, stream>>>(g_pos, g_neg, g_cnt);
    rrl_rows <<<NB, 256, 0, stream>>>(x4, t4, row_pq, row_cnt, n4);
    rrl_bin  <<<512, 256, 0, stream>>>(row_pq, row_cnt, img, g_pos, g_neg, g_cnt, nrows);
    rrl_final<<<1, 256, 0, stream>>>(g_pos, g_neg, g_cnt, out);
}

// Round 10
// 290.067 us; speedup vs baseline: 1.0163x; 1.0163x over previous
//
#include <hip/hip_runtime.h>

#define NGROUPS 256
#define NSHARD  8

typedef unsigned long long u64;
typedef __attribute__((ext_vector_type(4))) float f32x4;
typedef __attribute__((ext_vector_type(4))) int   i32x4;

// ---- DPP 32-lane sum (pure VALU, no LDS pipe) ----
// row_shr:1/2/4/8 then row_bcast:15. Afterwards lane31 = sum(lanes 0..31),
// lane63 = sum(lanes 32..63). bound_ctrl=1 -> OOB source lanes contribute 0.
template<int CTRL>
__device__ __forceinline__ float dpp_add_f(float x) {
    int s = __builtin_amdgcn_update_dpp(0, __float_as_int(x), CTRL, 0xF, 0xF, true);
    return x + __int_as_float(s);
}
template<int CTRL>
__device__ __forceinline__ int dpp_add_i(int x) {
    return x + __builtin_amdgcn_update_dpp(0, x, CTRL, 0xF, 0xF, true);
}
__device__ __forceinline__ float half_sum_f(float x) {
    x = dpp_add_f<0x111>(x);
    x = dpp_add_f<0x112>(x);
    x = dpp_add_f<0x114>(x);
    x = dpp_add_f<0x118>(x);
    x = dpp_add_f<0x142>(x);
    return x;
}
__device__ __forceinline__ int half_sum_i(int x) {
    x = dpp_add_i<0x111>(x);
    x = dpp_add_i<0x112>(x);
    x = dpp_add_i<0x114>(x);
    x = dpp_add_i<0x118>(x);
    x = dpp_add_i<0x142>(x);
    return x;
}

// Zero the sharded global accumulators (ws is re-poisoned to 0xAA each replay).
__global__ __launch_bounds__(256) void rrl_init(
    float* __restrict__ g_pos, float* __restrict__ g_neg, u64* __restrict__ g_cnt)
{
    for (int i = threadIdx.x; i < NSHARD * NGROUPS; i += 256) {
        g_pos[i] = 0.f; g_neg[i] = 0.f; g_cnt[i] = 0ULL;
    }
}

// One slot = one float4-pair. 32 consecutive lanes share one row (C=128
// floats = 32 float4), so the DPP half-sum gives the row partial; lanes
// 31/63 bin it into LDS by group (random groups -> few same-addr collisions).
__device__ __forceinline__ void proc_slot(
    f32x4 v, i32x4 t, int i, int lane31,
    const int* __restrict__ img_id,
    float* s_pos, float* s_neg, u64* s_cnt)
{
    float e0 = __expf(v[0]);
    float e1 = __expf(v[1]);
    float e2 = __expf(v[2]);
    float e3 = __expf(v[3]);
    float p = 0.f, q = 0.f;
    int pc = 0, qc = 0;
    if (t[0] != 0) { p += e0; ++pc; } else { q += e0; ++qc; }
    if (t[1] != 0) { p += e1; ++pc; } else { q += e1; ++qc; }
    if (t[2] != 0) { p += e2; ++pc; } else { q += e2; ++qc; }
    if (t[3] != 0) { p += e3; ++pc; } else { q += e3; ++qc; }
    int cnt = pc | (qc << 16);           // per-row fields <= 128 < 2^16
    p   = half_sum_f(p);
    q   = half_sum_f(q);
    cnt = half_sum_i(cnt);
    if (lane31 == 31) {                  // lanes 31 and 63 hold the half sums
        int r = i >> 5;                  // this lane's own row
        int g = img_id[r];
        atomicAdd(&s_pos[g], p);
        atomicAdd(&s_neg[g], q);
        atomicAdd(&s_cnt[g], ((u64)(unsigned)(cnt >> 16) << 32) | (u64)(cnt & 0xffff));
    }
}

// Fused pass: contiguous per-block spans (4096 slots = 64KB x + 64KB t),
// explicit 2-deep double-buffer of 4-slot load sets (8 dwordx4 in flight),
// DPP row-reduce -> LDS group atomics -> sharded global flush.
#define LOAD_SET(P, I) \
    v##P##0 = x4[(I)];        t##P##0 = t4[(I)];        \
    v##P##1 = x4[(I) + 256];  t##P##1 = t4[(I) + 256];  \
    v##P##2 = x4[(I) + 512];  t##P##2 = t4[(I) + 512];  \
    v##P##3 = x4[(I) + 768];  t##P##3 = t4[(I) + 768];

#define FENCE_SET(P) \
    asm volatile("" : "+v"(v##P##0), "+v"(v##P##1), "+v"(v##P##2), "+v"(v##P##3), \
                      "+v"(t##P##0), "+v"(t##P##1), "+v"(t##P##2), "+v"(t##P##3));

#define PROC_SET(P, I) \
    proc_slot(v##P##0, t##P##0, (I),       lane31, img_id, s_pos, s_neg, s_cnt); \
    proc_slot(v##P##1, t##P##1, (I) + 256, lane31, img_id, s_pos, s_neg, s_cnt); \
    proc_slot(v##P##2, t##P##2, (I) + 512, lane31, img_id, s_pos, s_neg, s_cnt); \
    proc_slot(v##P##3, t##P##3, (I) + 768, lane31, img_id, s_pos, s_neg, s_cnt);

__global__ __launch_bounds__(256, 4) void rrl_main(
    const f32x4* __restrict__ x4,
    const i32x4* __restrict__ t4,
    const int*   __restrict__ img_id,
    float* __restrict__ g_pos,      // [NSHARD][NGROUPS]
    float* __restrict__ g_neg,
    u64*   __restrict__ g_cnt,      // hi32 = neg count, lo32 = pos count
    int n4, int spb)
{
    __shared__ float s_pos[NGROUPS];
    __shared__ float s_neg[NGROUPS];
    __shared__ u64   s_cnt[NGROUPS];
    for (int k = threadIdx.x; k < NGROUPS; k += 256) {
        s_pos[k] = 0.f; s_neg[k] = 0.f; s_cnt[k] = 0ULL;
    }
    __syncthreads();

    const int tid    = threadIdx.x;
    const int lane31 = tid & 31;
    const int bstart = blockIdx.x * spb;

    if (bstart < n4) {
        if (bstart + 4096 <= n4 && spb == 4096) {
            // Fast path: full 4096-slot span, 4 sets of 1024, 2-deep pipeline.
            const int i0 = bstart + tid;
            f32x4 vA0, vA1, vA2, vA3, vB0, vB1, vB2, vB3;
            i32x4 tA0, tA1, tA2, tA3, tB0, tB1, tB2, tB3;
            LOAD_SET(A, i0)
            LOAD_SET(B, i0 + 1024)
            FENCE_SET(A)
            PROC_SET(A, i0)
            LOAD_SET(A, i0 + 2048)
            FENCE_SET(B)
            PROC_SET(B, i0 + 1024)
            LOAD_SET(B, i0 + 3072)
            FENCE_SET(A)
            PROC_SET(A, i0 + 2048)
            FENCE_SET(B)
            PROC_SET(B, i0 + 3072)
        } else {
            // Generic tail path (n4 is a multiple of 32, so each 32-lane
            // half is fully active or fully inactive -> DPP stays valid).
            const int bend = min(bstart + spb, n4);
            for (int i = bstart + tid; i < bend; i += 256) {
                proc_slot(x4[i], t4[i], i, lane31, img_id, s_pos, s_neg, s_cnt);
            }
        }
    }
    __syncthreads();

    const int shard = (blockIdx.x & (NSHARD - 1)) * NGROUPS;
    for (int g = tid; g < NGROUPS; g += 256) {
        atomicAdd(&g_pos[shard + g], s_pos[g]);
        atomicAdd(&g_neg[shard + g], s_neg[g]);
        atomicAdd(&g_cnt[shard + g], s_cnt[g]);
    }
}

// Final: one block; thread g merges 8 shards, computes loss_g, reduces.
__global__ __launch_bounds__(256) void rrl_final(
    const float* __restrict__ g_pos,
    const float* __restrict__ g_neg,
    const u64*   __restrict__ g_cnt,
    float* __restrict__ out)
{
    const int g = threadIdx.x;
    double pos_sum = 0.0, neg_sum = 0.0;
    u64 cc = 0ULL;
    #pragma unroll
    for (int s = 0; s < NSHARD; ++s) {
        pos_sum += (double)g_pos[s * NGROUPS + g];
        neg_sum += (double)g_neg[s * NGROUPS + g];
        cc      += g_cnt[s * NGROUPS + g];
    }
    long long pc = (long long)(cc & 0xffffffffULL);
    long long nc = (long long)(cc >> 32);
    long long count = pc + nc;

    // Expected sum of the k = min(pc, nc) randomly-sampled negatives:
    // neg_sum * k / nc (exact when pc >= nc: all negatives selected).
    double sel = 0.0;
    if (nc > 0) {
        long long k = (pc < nc) ? pc : nc;
        sel = neg_sum * ((double)k / (double)nc);
    }
    double loss = 0.0;
    if (pc > 0) loss = -log(pos_sum / (pos_sum + sel));
    int present = (count > 0) ? 1 : 0;

    __shared__ double sl[256];
    __shared__ int    sp[256];
    sl[g] = loss; sp[g] = present;
    __syncthreads();
    for (int off = 128; off > 0; off >>= 1) {
        if (g < off) { sl[g] += sl[g + off]; sp[g] += sp[g + off]; }
        __syncthreads();
    }
    if (g == 0) {
        double npres = (sp[0] > 0) ? (double)sp[0] : 1.0;
        out[0] = (float)(sl[0] / npres);
    }
}

extern "C" void kernel_launch(void* const* d_in, const int* in_sizes, int n_in,
                              void* d_out, int out_size, void* d_ws, size_t ws_size,
                              hipStream_t stream) {
    const f32x4* x4  = (const f32x4*)d_in[0];
    const i32x4* t4  = (const i32x4*)d_in[1];
    const int*   img = (const int*)d_in[2];
    float* out = (float*)d_out;

    const int NC = in_sizes[0];       // N * C
    const int n4 = NC / 4;            // float4 count (C=128 divisible by 4)

    // ws: [NSHARD][NGROUPS] f32 pos, f32 neg, u64 cnt (~32 KB).
    char* w = (char*)d_ws;
    float* g_pos = (float*)w;  w += (size_t)NSHARD * NGROUPS * 4;
    float* g_neg = (float*)w;  w += (size_t)NSHARD * NGROUPS * 4;
    u64*   g_cnt = (u64*)w;

    const int NB  = 2048;
    // Span per block, rounded to 1024 (set granularity). For N=262144, C=128:
    // n4 = 8388608 = 2048 * 4096 exactly -> all blocks take the fast path.
    int spb = (n4 + NB - 1) / NB;
    spb = (spb + 1023) & ~1023;

    rrl_init <<<1, 256, 0, stream>>>(g_pos, g_neg, g_cnt);
    rrl_main <<<NB, 256, 0, stream>>>(x4, t4, img, g_pos, g_neg, g_cnt, n4, spb);
    rrl_final<<<1, 256, 0, stream>>>(g_pos, g_neg, g_cnt, out);
}